// Round 4
// baseline (580.906 us; speedup 1.0000x reference)
//
#include <hip/hip_runtime.h>
#include <hip/hip_bf16.h>
#include <cstdint>

#define N_NODES 50000
#define N_EDGES 1600000
#define DIM 128
#define NREL 8
#define LN_EPS 1e-5f

#define NKEYS (N_NODES * NREL)          // 400000
#define SCAN_CHUNK 1024                 // elems per scan block (256 thr x 4)
#define SCAN_NBLK ((NKEYS + SCAN_CHUNK - 1) / SCAN_CHUNK)  // 391

typedef unsigned short ushort_t;
typedef short short8 __attribute__((ext_vector_type(8)));
typedef float f32x4 __attribute__((ext_vector_type(4)));

__device__ inline ushort_t f2bf(float f) {
    union { float f; unsigned u; } v; v.f = f;
    unsigned r = (v.u + 0x7FFFu + ((v.u >> 16) & 1u)) >> 16;
    return (ushort_t)r;
}
__device__ inline float bf2f(unsigned u) {
    union { unsigned u; float f; } v; v.u = u << 16;
    return v.f;
}

// ---------------------------------------------------------------------------
// Count edges per (dst, rel) key.
// ---------------------------------------------------------------------------
__global__ __launch_bounds__(256) void count_kernel(const int* __restrict__ ei,
                                                    const int* __restrict__ et,
                                                    unsigned* __restrict__ cnt) {
    int e = blockIdx.x * 256 + threadIdx.x;
    if (e < N_EDGES) {
        int dst = ei[N_EDGES + e];
        int t   = et[e];
        atomicAdd(&cnt[(size_t)dst * NREL + t], 1u);
    }
}

// ---------------------------------------------------------------------------
// Exclusive prefix scan over cnt[NKEYS] -> offs[NKEYS], 3-kernel scheme.
// ---------------------------------------------------------------------------
__global__ __launch_bounds__(256) void scan1_kernel(const unsigned* __restrict__ cnt,
                                                    unsigned* __restrict__ offs,
                                                    unsigned* __restrict__ bsums) {
    __shared__ unsigned lds[256];
    int tid = threadIdx.x;
    int i0  = blockIdx.x * SCAN_CHUNK + tid * 4;
    unsigned v[4], incl[4];
    unsigned s = 0;
#pragma unroll
    for (int j = 0; j < 4; ++j) {
        v[j] = (i0 + j < NKEYS) ? cnt[i0 + j] : 0u;
        s += v[j];
        incl[j] = s;
    }
    lds[tid] = s;
    __syncthreads();
    for (int off = 1; off < 256; off <<= 1) {
        unsigned a = (tid >= off) ? lds[tid - off] : 0u;
        __syncthreads();
        lds[tid] += a;
        __syncthreads();
    }
    unsigned base = lds[tid] - s;
#pragma unroll
    for (int j = 0; j < 4; ++j) {
        if (i0 + j < NKEYS) offs[i0 + j] = base + incl[j] - v[j];
    }
    if (tid == 255) bsums[blockIdx.x] = lds[255];
}

__global__ __launch_bounds__(512) void scan2_kernel(unsigned* __restrict__ bsums) {
    __shared__ unsigned lds[512];
    int tid = threadIdx.x;
    unsigned v = (tid < SCAN_NBLK) ? bsums[tid] : 0u;
    lds[tid] = v;
    __syncthreads();
    for (int off = 1; off < 512; off <<= 1) {
        unsigned a = (tid >= off) ? lds[tid - off] : 0u;
        __syncthreads();
        lds[tid] += a;
        __syncthreads();
    }
    if (tid < SCAN_NBLK) bsums[tid] = lds[tid] - v;
}

__global__ __launch_bounds__(256) void scan3_kernel(unsigned* __restrict__ offs,
                                                    const unsigned* __restrict__ bsums) {
    int i0 = blockIdx.x * SCAN_CHUNK + threadIdx.x * 4;
    unsigned add = bsums[blockIdx.x];
#pragma unroll
    for (int j = 0; j < 4; ++j)
        if (i0 + j < NKEYS) offs[i0 + j] += add;
}

// ---------------------------------------------------------------------------
// Scatter src ids into bucket-sorted order (counting sort fill).
// ---------------------------------------------------------------------------
__global__ __launch_bounds__(256) void fill_kernel(const int* __restrict__ ei,
                                                   const int* __restrict__ et,
                                                   const unsigned* __restrict__ offs,
                                                   unsigned* __restrict__ fill,
                                                   int* __restrict__ sorted_src) {
    int e = blockIdx.x * 256 + threadIdx.x;
    if (e < N_EDGES) {
        int dst = ei[N_EDGES + e];
        int key = dst * NREL + et[e];
        unsigned p = offs[key] + atomicAdd(&fill[key], 1u);
        sorted_src[p] = ei[e];
    }
}

// ---------------------------------------------------------------------------
// Convert + transpose W into Bt[9][feat n][k] bf16 (Bt[8] = W_root^T).
// ---------------------------------------------------------------------------
__global__ __launch_bounds__(256) void bt_kernel(const float* __restrict__ W_rel,
                                                 const float* __restrict__ W_root,
                                                 ushort_t* __restrict__ Bt) {
    int i = blockIdx.x * 256 + threadIdx.x;
    if (i >= 9 * DIM * DIM) return;
    int r   = i >> 14;
    int rem = i & 16383;
    int n   = rem >> 7;
    int k   = rem & 127;
    const float* W = (r < NREL) ? (W_rel + (size_t)r * DIM * DIM) : W_root;
    Bt[i] = f2bf(W[(size_t)k * DIM + n]);
}

// ---------------------------------------------------------------------------
// x (fp32) -> xb (bf16), float4 -> uint2 per thread.
// ---------------------------------------------------------------------------
__global__ __launch_bounds__(256) void xb_kernel(const float* __restrict__ x,
                                                 ushort_t* __restrict__ xb) {
    int i = blockIdx.x * 256 + threadIdx.x;   // float4 index
    if (i >= N_NODES * DIM / 4) return;
    float4 v = ((const float4*)x)[i];
    unsigned lo = (unsigned)f2bf(v.x) | ((unsigned)f2bf(v.y) << 16);
    unsigned hi = (unsigned)f2bf(v.z) | ((unsigned)f2bf(v.w) << 16);
    ((uint2*)xb)[i] = make_uint2(lo, hi);
}

// ---------------------------------------------------------------------------
// Fused: per 64-node tile, for each of 9 "relations" (8 rel + root):
//   build A tile in LDS (bucket means gathered from xb / coalesced xb copy),
//   stage full 128x128 W^T tile, 32x mfma_f32_16x16x32_bf16.
// Epilogue: bias + LayerNorm + ReLU fused (row = one 16-lane group x 8 regs).
// LDS: Afull 16 KB + Bfull 32 KB = 48 KB -> 3 blocks/CU.
// ---------------------------------------------------------------------------
__global__ __launch_bounds__(256) void fused_kernel(const unsigned* __restrict__ offs,
                                                    const unsigned* __restrict__ cnt,
                                                    const int* __restrict__ sorted_src,
                                                    const ushort_t* __restrict__ xb,
                                                    const ushort_t* __restrict__ Bt,
                                                    const float* __restrict__ bias,
                                                    const float* __restrict__ gamma,
                                                    const float* __restrict__ beta,
                                                    float* __restrict__ out) {
    __shared__ __align__(16) ushort_t Afull[16][64][8];   // [k-chunk][row][8]
    __shared__ __align__(16) ushort_t Bfull[16][128][8];  // [k-chunk][feat][8]

    int tid  = threadIdx.x;
    int w    = tid >> 6;
    int lane = tid & 63;
    int m    = lane & 15;
    int quad = lane >> 4;
    int v0   = blockIdx.x * 64;

    f32x4 acc[8];
#pragma unroll
    for (int j = 0; j < 8; ++j) acc[j] = (f32x4){0.f, 0.f, 0.f, 0.f};

    for (int rel = 0; rel < 9; ++rel) {
        // ---- stage B: full 128x128 bf16 relation tile (issue loads first) ----
#pragma unroll
        for (int p = 0; p < 8; ++p) {
            int i = tid + 256 * p;            // 0..2047 16B-chunks
            int n = i >> 4, c = i & 15;
            uint4 bv = *(const uint4*)(Bt + ((size_t)rel * DIM + n) * DIM + c * 8);
            *(uint4*)&Bfull[c][n][0] = bv;
        }

        // ---- build A tile ----
        if (rel < NREL) {
            // half-wave per bucket: lanes 0-31 bucket a, 32-63 bucket b
            int sub = lane >> 5, sl = lane & 31;
#pragma unroll
            for (int it = 0; it < 8; ++it) {
                int vloc = w * 16 + it * 2 + sub;
                int v    = v0 + vloc;
                float a0 = 0.f, a1 = 0.f, a2 = 0.f, a3 = 0.f;
                unsigned mc = 0;
                if (v < N_NODES) {
                    int key = v * NREL + rel;
                    unsigned st = offs[key];
                    mc = cnt[key];
                    unsigned en = st + mc;
                    unsigned e = st;
                    for (; e + 1 < en; e += 2) {
                        int s0 = sorted_src[e];
                        int s1 = sorted_src[e + 1];
                        uint2 d0 = *(const uint2*)(xb + (size_t)s0 * DIM + sl * 4);
                        uint2 d1 = *(const uint2*)(xb + (size_t)s1 * DIM + sl * 4);
                        a0 += bf2f(d0.x & 0xffffu) + bf2f(d1.x & 0xffffu);
                        a1 += bf2f(d0.x >> 16)     + bf2f(d1.x >> 16);
                        a2 += bf2f(d0.y & 0xffffu) + bf2f(d1.y & 0xffffu);
                        a3 += bf2f(d0.y >> 16)     + bf2f(d1.y >> 16);
                    }
                    if (e < en) {
                        int s0 = sorted_src[e];
                        uint2 d0 = *(const uint2*)(xb + (size_t)s0 * DIM + sl * 4);
                        a0 += bf2f(d0.x & 0xffffu);
                        a1 += bf2f(d0.x >> 16);
                        a2 += bf2f(d0.y & 0xffffu);
                        a3 += bf2f(d0.y >> 16);
                    }
                }
                float inv = 1.0f / fmaxf((float)mc, 1.0f);
                unsigned lo = (unsigned)f2bf(a0 * inv) | ((unsigned)f2bf(a1 * inv) << 16);
                unsigned hi = (unsigned)f2bf(a2 * inv) | ((unsigned)f2bf(a3 * inv) << 16);
                // lane sl covers k = sl*4..sl*4+3 -> chunk sl>>1, half (sl&1)
                *(uint2*)&Afull[sl >> 1][vloc][(sl & 1) * 4] = make_uint2(lo, hi);
            }
        } else {
            // root: coalesced copy of xb rows
#pragma unroll
            for (int p = 0; p < 4; ++p) {
                int i = tid + 256 * p;        // 0..1023 16B-chunks
                int v = i >> 4, c = i & 15;
                uint4 d = make_uint4(0, 0, 0, 0);
                if (v0 + v < N_NODES)
                    d = *(const uint4*)(xb + (size_t)(v0 + v) * DIM + c * 8);
                *(uint4*)&Afull[c][v][0] = d;
            }
        }
        __syncthreads();

        // ---- 32 MFMA per relation (4 K-steps of 32 x 8 feat-blocks) ----
#pragma unroll
        for (int t4 = 0; t4 < 4; ++t4) {
            short8 af = *(const short8*)&Afull[t4 * 4 + quad][w * 16 + m][0];
#pragma unroll
            for (int j = 0; j < 8; ++j) {
                short8 bf = *(const short8*)&Bfull[t4 * 4 + quad][j * 16 + m][0];
                acc[j] = __builtin_amdgcn_mfma_f32_16x16x32_bf16(af, bf, acc[j], 0, 0, 0);
            }
        }
        __syncthreads();
    }

    // ---- epilogue: bias + LayerNorm + ReLU, write once ----
    float bj[8], gj[8], btj[8];
#pragma unroll
    for (int j = 0; j < 8; ++j) {
        bj[j]  = bias[j * 16 + m];
        gj[j]  = gamma[j * 16 + m];
        btj[j] = beta[j * 16 + m];
    }
#pragma unroll
    for (int i = 0; i < 4; ++i) {
        float s = 0.f, sq = 0.f;
#pragma unroll
        for (int j = 0; j < 8; ++j) {
            float v = acc[j][i] + bj[j];
            s  += v;
            sq += v * v;
        }
#pragma unroll
        for (int off = 1; off < 16; off <<= 1) {
            s  += __shfl_xor(s, off, 64);
            sq += __shfl_xor(sq, off, 64);
        }
        float mean = s * (1.0f / DIM);
        float var  = sq * (1.0f / DIM) - mean * mean;
        float rstd = rsqrtf(var + LN_EPS);
        int node = v0 + w * 16 + quad * 4 + i;
        if (node < N_NODES) {
#pragma unroll
            for (int j = 0; j < 8; ++j) {
                float v = acc[j][i] + bj[j];
                v = (v - mean) * rstd * gj[j] + btj[j];
                out[(size_t)node * DIM + j * 16 + m] = fmaxf(v, 0.f);
            }
        }
    }
}

// ---------------------------------------------------------------------------
extern "C" void kernel_launch(void* const* d_in, const int* in_sizes, int n_in,
                              void* d_out, int out_size, void* d_ws, size_t ws_size,
                              hipStream_t stream) {
    const float* x      = (const float*)d_in[0];
    const int*   ei     = (const int*)d_in[1];
    const int*   et     = (const int*)d_in[2];
    const float* W_rel  = (const float*)d_in[4];
    const float* W_root = (const float*)d_in[5];
    const float* bias   = (const float*)d_in[6];
    const float* gamma  = (const float*)d_in[7];
    const float* beta   = (const float*)d_in[8];
    float*       out    = (float*)d_out;

    // ---- workspace layout (~24.5 MB total) ----
    char* ws = (char*)d_ws;
    size_t off = 0;
    auto alloc = [&](size_t bytes) { char* p = ws + off; off = (off + bytes + 255) & ~(size_t)255; return p; };
    unsigned* cnt        = (unsigned*)alloc((size_t)NKEYS * 4);
    unsigned* offs       = (unsigned*)alloc((size_t)NKEYS * 4);
    unsigned* fill       = (unsigned*)alloc((size_t)NKEYS * 4);
    unsigned* bsums      = (unsigned*)alloc((size_t)SCAN_NBLK * 4);
    int*      sorted_src = (int*)alloc((size_t)N_EDGES * 4);
    ushort_t* Bt         = (ushort_t*)alloc((size_t)9 * DIM * DIM * 2);
    ushort_t* xb         = (ushort_t*)alloc((size_t)N_NODES * DIM * 2);

    // ---- build counting sort ----
    hipMemsetAsync(cnt, 0, (size_t)NKEYS * 4, stream);
    hipMemsetAsync(fill, 0, (size_t)NKEYS * 4, stream);
    count_kernel<<<(N_EDGES + 255) / 256, 256, 0, stream>>>(ei, et, cnt);
    scan1_kernel<<<SCAN_NBLK, 256, 0, stream>>>(cnt, offs, bsums);
    scan2_kernel<<<1, 512, 0, stream>>>(bsums);
    scan3_kernel<<<SCAN_NBLK, 256, 0, stream>>>(offs, bsums);
    fill_kernel<<<(N_EDGES + 255) / 256, 256, 0, stream>>>(ei, et, offs, fill, sorted_src);

    // ---- precompute bf16 operands ----
    bt_kernel<<<(9 * DIM * DIM + 255) / 256, 256, 0, stream>>>(W_rel, W_root, Bt);
    xb_kernel<<<(N_NODES * DIM / 4 + 255) / 256, 256, 0, stream>>>(x, xb);

    // ---- fused aggregate + GEMM + LN ----
    fused_kernel<<<(N_NODES + 63) / 64, 256, 0, stream>>>(offs, cnt, sorted_src, xb, Bt,
                                                          bias, gamma, beta, out);
}

// Round 5
// 521.781 us; speedup vs baseline: 1.1133x; 1.1133x over previous
//
#include <hip/hip_runtime.h>
#include <hip/hip_bf16.h>
#include <cstdint>

#define N_NODES 50000
#define N_EDGES 1600000
#define DIM 128
#define NREL 8
#define LN_EPS 1e-5f

#define NKEYS (N_NODES * NREL)          // 400000
#define SCAN_CHUNK 1024                 // elems per scan block (256 thr x 4)
#define SCAN_NBLK ((NKEYS + SCAN_CHUNK - 1) / SCAN_CHUNK)  // 391

typedef unsigned short ushort_t;
typedef short short8 __attribute__((ext_vector_type(8)));
typedef float f32x4 __attribute__((ext_vector_type(4)));

__device__ inline ushort_t f2bf(float f) {
    union { float f; unsigned u; } v; v.f = f;
    unsigned r = (v.u + 0x7FFFu + ((v.u >> 16) & 1u)) >> 16;
    return (ushort_t)r;
}
__device__ inline float bf_lo(unsigned u) {   // low 16 bits -> float
    union { unsigned u; float f; } v; v.u = u << 16;
    return v.f;
}
__device__ inline float bf_hi(unsigned u) {   // high 16 bits -> float
    union { unsigned u; float f; } v; v.u = u & 0xffff0000u;
    return v.f;
}

// ---------------------------------------------------------------------------
// Count edges per (dst, rel) key.
// ---------------------------------------------------------------------------
__global__ __launch_bounds__(256) void count_kernel(const int* __restrict__ ei,
                                                    const int* __restrict__ et,
                                                    unsigned* __restrict__ cnt) {
    int e = blockIdx.x * 256 + threadIdx.x;
    if (e < N_EDGES) {
        int dst = ei[N_EDGES + e];
        int t   = et[e];
        atomicAdd(&cnt[(size_t)dst * NREL + t], 1u);
    }
}

// ---------------------------------------------------------------------------
// Exclusive prefix scan over cnt[NKEYS] -> offs[NKEYS], 3-kernel scheme.
// ---------------------------------------------------------------------------
__global__ __launch_bounds__(256) void scan1_kernel(const unsigned* __restrict__ cnt,
                                                    unsigned* __restrict__ offs,
                                                    unsigned* __restrict__ bsums) {
    __shared__ unsigned lds[256];
    int tid = threadIdx.x;
    int i0  = blockIdx.x * SCAN_CHUNK + tid * 4;
    unsigned v[4], incl[4];
    unsigned s = 0;
#pragma unroll
    for (int j = 0; j < 4; ++j) {
        v[j] = (i0 + j < NKEYS) ? cnt[i0 + j] : 0u;
        s += v[j];
        incl[j] = s;
    }
    lds[tid] = s;
    __syncthreads();
    for (int off = 1; off < 256; off <<= 1) {
        unsigned a = (tid >= off) ? lds[tid - off] : 0u;
        __syncthreads();
        lds[tid] += a;
        __syncthreads();
    }
    unsigned base = lds[tid] - s;
#pragma unroll
    for (int j = 0; j < 4; ++j) {
        if (i0 + j < NKEYS) offs[i0 + j] = base + incl[j] - v[j];
    }
    if (tid == 255) bsums[blockIdx.x] = lds[255];
}

__global__ __launch_bounds__(512) void scan2_kernel(unsigned* __restrict__ bsums) {
    __shared__ unsigned lds[512];
    int tid = threadIdx.x;
    unsigned v = (tid < SCAN_NBLK) ? bsums[tid] : 0u;
    lds[tid] = v;
    __syncthreads();
    for (int off = 1; off < 512; off <<= 1) {
        unsigned a = (tid >= off) ? lds[tid - off] : 0u;
        __syncthreads();
        lds[tid] += a;
        __syncthreads();
    }
    if (tid < SCAN_NBLK) bsums[tid] = lds[tid] - v;
}

__global__ __launch_bounds__(256) void scan3_kernel(unsigned* __restrict__ offs,
                                                    const unsigned* __restrict__ bsums) {
    int i0 = blockIdx.x * SCAN_CHUNK + threadIdx.x * 4;
    unsigned add = bsums[blockIdx.x];
#pragma unroll
    for (int j = 0; j < 4; ++j)
        if (i0 + j < NKEYS) offs[i0 + j] += add;
}

// ---------------------------------------------------------------------------
// Scatter src ids into bucket-sorted order (counting sort fill).
// ---------------------------------------------------------------------------
__global__ __launch_bounds__(256) void fill_kernel(const int* __restrict__ ei,
                                                   const int* __restrict__ et,
                                                   const unsigned* __restrict__ offs,
                                                   unsigned* __restrict__ fill,
                                                   int* __restrict__ sorted_src) {
    int e = blockIdx.x * 256 + threadIdx.x;
    if (e < N_EDGES) {
        int dst = ei[N_EDGES + e];
        int key = dst * NREL + et[e];
        unsigned p = offs[key] + atomicAdd(&fill[key], 1u);
        sorted_src[p] = ei[e];
    }
}

// ---------------------------------------------------------------------------
// Convert + transpose W into Bt[9][feat n][k] bf16 (Bt[8] = W_root^T).
// ---------------------------------------------------------------------------
__global__ __launch_bounds__(256) void bt_kernel(const float* __restrict__ W_rel,
                                                 const float* __restrict__ W_root,
                                                 ushort_t* __restrict__ Bt) {
    int i = blockIdx.x * 256 + threadIdx.x;
    if (i >= 9 * DIM * DIM) return;
    int r   = i >> 14;
    int rem = i & 16383;
    int n   = rem >> 7;
    int k   = rem & 127;
    const float* W = (r < NREL) ? (W_rel + (size_t)r * DIM * DIM) : W_root;
    Bt[i] = f2bf(W[(size_t)k * DIM + n]);
}

// ---------------------------------------------------------------------------
// x (fp32) -> xb (bf16), float4 -> uint2 per thread.
// ---------------------------------------------------------------------------
__global__ __launch_bounds__(256) void xb_kernel(const float* __restrict__ x,
                                                 ushort_t* __restrict__ xb) {
    int i = blockIdx.x * 256 + threadIdx.x;   // float4 index
    if (i >= N_NODES * DIM / 4) return;
    float4 v = ((const float4*)x)[i];
    unsigned lo = (unsigned)f2bf(v.x) | ((unsigned)f2bf(v.y) << 16);
    unsigned hi = (unsigned)f2bf(v.z) | ((unsigned)f2bf(v.w) << 16);
    ((uint2*)xb)[i] = make_uint2(lo, hi);
}

// ---------------------------------------------------------------------------
// Half-wave (32 lanes) per (node, rel) bucket: mean of xb[src] rows -> h bf16.
// fp32 accumulate via shift/and unpack. Empty buckets write zeros.
// h layout: h[node*cr + rl][DIM] (chunk-local).
// ---------------------------------------------------------------------------
__global__ __launch_bounds__(256) void aggregate_kernel(const unsigned* __restrict__ offs,
                                                        const unsigned* __restrict__ cnt,
                                                        const int* __restrict__ sorted_src,
                                                        const ushort_t* __restrict__ xb,
                                                        ushort_t* __restrict__ h,
                                                        int r0, int cr) {
    int g  = blockIdx.x * 8 + (threadIdx.x >> 5);   // bucket id
    int sl = threadIdx.x & 31;                      // lane covers 4 feats
    int total = N_NODES * cr;
    if (g >= total) return;
    int n  = g / cr;
    int rl = g - n * cr;
    int key = n * NREL + r0 + rl;
    unsigned st = offs[key];
    unsigned mc = cnt[key];
    unsigned en = st + mc;
    float a0 = 0.f, a1 = 0.f, a2 = 0.f, a3 = 0.f;
    unsigned e = st;
    for (; e + 1 < en; e += 2) {
        int s0 = sorted_src[e];
        int s1 = sorted_src[e + 1];
        uint2 d0 = *(const uint2*)(xb + (size_t)s0 * DIM + sl * 4);
        uint2 d1 = *(const uint2*)(xb + (size_t)s1 * DIM + sl * 4);
        a0 += bf_lo(d0.x) + bf_lo(d1.x);
        a1 += bf_hi(d0.x) + bf_hi(d1.x);
        a2 += bf_lo(d0.y) + bf_lo(d1.y);
        a3 += bf_hi(d0.y) + bf_hi(d1.y);
    }
    if (e < en) {
        int s0 = sorted_src[e];
        uint2 d0 = *(const uint2*)(xb + (size_t)s0 * DIM + sl * 4);
        a0 += bf_lo(d0.x);
        a1 += bf_hi(d0.x);
        a2 += bf_lo(d0.y);
        a3 += bf_hi(d0.y);
    }
    float inv = 1.0f / fmaxf((float)mc, 1.0f);
    unsigned lo = (unsigned)f2bf(a0 * inv) | ((unsigned)f2bf(a1 * inv) << 16);
    unsigned hi = (unsigned)f2bf(a2 * inv) | ((unsigned)f2bf(a3 * inv) << 16);
    ((uint2*)(h + (size_t)g * DIM))[sl] = make_uint2(lo, hi);
}

// ---------------------------------------------------------------------------
// Zero-LDS, zero-barrier MFMA GEMM with optional fused bias+LN+ReLU.
// One wave = 16 nodes x 128 feats. A-frags loaded directly from h/xb
// (lane m = node row, quad*8 = k offset, 16B each); B-frags directly from
// Bt (L1/L2-hot). 4 K-steps x 8 feat-blocks per relation.
// ---------------------------------------------------------------------------
__global__ __launch_bounds__(256) void gemm_ln_kernel(const ushort_t* __restrict__ h,
                                                      int cr, int r0,
                                                      const ushort_t* __restrict__ xb,
                                                      const ushort_t* __restrict__ Bt,
                                                      int include_root,
                                                      const float* __restrict__ bias,
                                                      const float* __restrict__ gamma,
                                                      const float* __restrict__ beta,
                                                      float* __restrict__ out,
                                                      int accumulate, int do_ln) {
    int w    = threadIdx.x >> 6;
    int lane = threadIdx.x & 63;
    int m    = lane & 15;
    int quad = lane >> 4;
    int tile = blockIdx.x * 4 + w;            // 16-node strip
    int n0   = tile * 16;
    if (n0 >= N_NODES) return;
    int arow = n0 + m;                        // node row this lane feeds to MFMA
    if (arow >= N_NODES) arow = N_NODES - 1;  // clamp (results discarded)

    const ushort_t* hrow = h  + (size_t)arow * cr * DIM;
    const ushort_t* xrow = xb + (size_t)arow * DIM;

    f32x4 acc[8];
#pragma unroll
    for (int j = 0; j < 8; ++j) acc[j] = (f32x4){0.f, 0.f, 0.f, 0.f};

    int nrel = cr + include_root;
    for (int rr = 0; rr < nrel; ++rr) {
        const ushort_t* abase = (rr < cr) ? (hrow + (size_t)rr * DIM) : xrow;
        int rel = (rr < cr) ? (r0 + rr) : NREL;
        const ushort_t* bbase = Bt + (size_t)rel * DIM * DIM + (size_t)m * DIM + quad * 8;
#pragma unroll
        for (int t = 0; t < 4; ++t) {
            short8 af = *(const short8*)(abase + t * 32 + quad * 8);
#pragma unroll
            for (int j = 0; j < 8; ++j) {
                short8 bf = *(const short8*)(bbase + (size_t)j * 16 * DIM + t * 32);
                acc[j] = __builtin_amdgcn_mfma_f32_16x16x32_bf16(af, bf, acc[j], 0, 0, 0);
            }
        }
    }

    if (do_ln) {
        float bj[8], gj[8], btj[8];
#pragma unroll
        for (int j = 0; j < 8; ++j) {
            bj[j]  = bias[j * 16 + m];
            gj[j]  = gamma[j * 16 + m];
            btj[j] = beta[j * 16 + m];
        }
#pragma unroll
        for (int i = 0; i < 4; ++i) {
            float s = 0.f, sq = 0.f;
#pragma unroll
            for (int j = 0; j < 8; ++j) {
                float v = acc[j][i] + bj[j];
                s  += v;
                sq += v * v;
            }
#pragma unroll
            for (int off = 1; off < 16; off <<= 1) {
                s  += __shfl_xor(s, off, 64);
                sq += __shfl_xor(sq, off, 64);
            }
            float mean = s * (1.0f / DIM);
            float var  = sq * (1.0f / DIM) - mean * mean;
            float rstd = rsqrtf(var + LN_EPS);
            int node = n0 + quad * 4 + i;
            if (node < N_NODES) {
#pragma unroll
                for (int j = 0; j < 8; ++j) {
                    float v = acc[j][i] + bj[j];
                    v = (v - mean) * rstd * gj[j] + btj[j];
                    out[(size_t)node * DIM + j * 16 + m] = fmaxf(v, 0.f);
                }
            }
        }
    } else {
#pragma unroll
        for (int i = 0; i < 4; ++i) {
            int node = n0 + quad * 4 + i;
            if (node < N_NODES) {
#pragma unroll
                for (int j = 0; j < 8; ++j) {
                    size_t o = (size_t)node * DIM + j * 16 + m;
                    float v = acc[j][i];
                    if (accumulate) v += out[o];
                    out[o] = v;
                }
            }
        }
    }
}

// ---------------------------------------------------------------------------
// Standalone bias + LayerNorm + ReLU (fallback for chunked path).
// ---------------------------------------------------------------------------
__global__ __launch_bounds__(256) void ln_kernel(float* __restrict__ out,
                                                 const float* __restrict__ bias,
                                                 const float* __restrict__ gamma,
                                                 const float* __restrict__ beta) {
    int row  = blockIdx.x * 4 + (threadIdx.x >> 6);
    int lane = threadIdx.x & 63;
    if (row >= N_NODES) return;
    float2 v = *(float2*)(out + (size_t)row * DIM + lane * 2);
    float2 bi = *(const float2*)(bias + lane * 2);
    v.x += bi.x;
    v.y += bi.y;
    float s  = v.x + v.y;
    float sq = v.x * v.x + v.y * v.y;
#pragma unroll
    for (int off = 32; off > 0; off >>= 1) {
        s  += __shfl_xor(s, off, 64);
        sq += __shfl_xor(sq, off, 64);
    }
    float mean = s * (1.0f / DIM);
    float var  = sq * (1.0f / DIM) - mean * mean;
    float rstd = rsqrtf(var + LN_EPS);
    float2 g = *(const float2*)(gamma + lane * 2);
    float2 b = *(const float2*)(beta + lane * 2);
    v.x = fmaxf((v.x - mean) * rstd * g.x + b.x, 0.f);
    v.y = fmaxf((v.y - mean) * rstd * g.y + b.y, 0.f);
    *(float2*)(out + (size_t)row * DIM + lane * 2) = v;
}

// ---------------------------------------------------------------------------
extern "C" void kernel_launch(void* const* d_in, const int* in_sizes, int n_in,
                              void* d_out, int out_size, void* d_ws, size_t ws_size,
                              hipStream_t stream) {
    const float* x      = (const float*)d_in[0];
    const int*   ei     = (const int*)d_in[1];
    const int*   et     = (const int*)d_in[2];
    const float* W_rel  = (const float*)d_in[4];
    const float* W_root = (const float*)d_in[5];
    const float* bias   = (const float*)d_in[6];
    const float* gamma  = (const float*)d_in[7];
    const float* beta   = (const float*)d_in[8];
    float*       out    = (float*)d_out;

    // ---- workspace layout ----
    char* ws = (char*)d_ws;
    size_t off = 0;
    auto alloc = [&](size_t bytes) { char* p = ws + off; off = (off + bytes + 255) & ~(size_t)255; return p; };
    unsigned* cnt        = (unsigned*)alloc((size_t)NKEYS * 4);
    unsigned* offs       = (unsigned*)alloc((size_t)NKEYS * 4);
    unsigned* fill       = (unsigned*)alloc((size_t)NKEYS * 4);
    unsigned* bsums      = (unsigned*)alloc((size_t)SCAN_NBLK * 4);
    int*      sorted_src = (int*)alloc((size_t)N_EDGES * 4);
    ushort_t* Bt         = (ushort_t*)alloc((size_t)9 * DIM * DIM * 2);
    ushort_t* xb         = (ushort_t*)alloc((size_t)N_NODES * DIM * 2);
    size_t fixedOff = off;
    ushort_t* h = (ushort_t*)(ws + fixedOff);
    size_t availB = ws_size > fixedOff ? ws_size - fixedOff : 0;
    size_t perRel = (size_t)N_NODES * DIM * 2;   // 12.8 MB per relation (bf16)
    int chunkR = (int)(availB / perRel);
    if (chunkR > NREL) chunkR = NREL;
    if (chunkR < 1)    chunkR = 1;

    // ---- build counting sort ----
    hipMemsetAsync(cnt, 0, (size_t)NKEYS * 4, stream);
    hipMemsetAsync(fill, 0, (size_t)NKEYS * 4, stream);
    count_kernel<<<(N_EDGES + 255) / 256, 256, 0, stream>>>(ei, et, cnt);
    scan1_kernel<<<SCAN_NBLK, 256, 0, stream>>>(cnt, offs, bsums);
    scan2_kernel<<<1, 512, 0, stream>>>(bsums);
    scan3_kernel<<<SCAN_NBLK, 256, 0, stream>>>(offs, bsums);
    fill_kernel<<<(N_EDGES + 255) / 256, 256, 0, stream>>>(ei, et, offs, fill, sorted_src);

    // ---- precompute bf16 operands ----
    bt_kernel<<<(9 * DIM * DIM + 255) / 256, 256, 0, stream>>>(W_rel, W_root, Bt);
    xb_kernel<<<(N_NODES * DIM / 4 + 255) / 256, 256, 0, stream>>>(x, xb);

    int gemmGrid = ((N_NODES + 15) / 16 + 3) / 4;   // 4 strips (waves) per block

    if (chunkR >= NREL) {
        // fully fused single pass: aggregate -> GEMM(+root)+bias+LN+ReLU
        int nbuck = N_NODES * NREL;
        aggregate_kernel<<<(nbuck + 7) / 8, 256, 0, stream>>>(offs, cnt, sorted_src, xb, h, 0, NREL);
        gemm_ln_kernel<<<gemmGrid, 256, 0, stream>>>(h, NREL, 0, xb, Bt, 1,
                                                     bias, gamma, beta, out, 0, 1);
    } else {
        for (int r0 = 0; r0 < NREL; r0 += chunkR) {
            int cr = (NREL - r0 < chunkR) ? (NREL - r0) : chunkR;
            int nbuck = N_NODES * cr;
            aggregate_kernel<<<(nbuck + 7) / 8, 256, 0, stream>>>(offs, cnt, sorted_src, xb, h, r0, cr);
            int include_root = (r0 + cr == NREL) ? 1 : 0;
            gemm_ln_kernel<<<gemmGrid, 256, 0, stream>>>(h, cr, r0, xb, Bt, include_root,
                                                         bias, gamma, beta, out,
                                                         r0 > 0 ? 1 : 0, 0);
        }
        ln_kernel<<<(N_NODES + 3) / 4, 256, 0, stream>>>(out, bias, gamma, beta);
    }
}

// Round 6
// 407.116 us; speedup vs baseline: 1.4269x; 1.2817x over previous
//
#include <hip/hip_runtime.h>
#include <hip/hip_bf16.h>
#include <cstdint>

#define N_NODES 50000
#define N_EDGES 1600000
#define DIM 128
#define NREL 8
#define LN_EPS 1e-5f

#define NKEYS (N_NODES * NREL)          // 400000
#define SCAN_CHUNK 1024                 // elems per scan block (256 thr x 4)
#define SCAN_NBLK ((NKEYS + SCAN_CHUNK - 1) / SCAN_CHUNK)  // 391

#define A_STRIDE 136                    // ushorts per LDS A row (128 + 8 pad)
#define B_STRIDE 136                    // ushorts per LDS B row

typedef unsigned short ushort_t;
typedef short short8 __attribute__((ext_vector_type(8)));
typedef float f32x4 __attribute__((ext_vector_type(4)));

__device__ inline ushort_t f2bf(float f) {
    union { float f; unsigned u; } v; v.f = f;
    unsigned r = (v.u + 0x7FFFu + ((v.u >> 16) & 1u)) >> 16;
    return (ushort_t)r;
}
__device__ inline float bf_lo(unsigned u) {
    union { unsigned u; float f; } v; v.u = u << 16;
    return v.f;
}
__device__ inline float bf_hi(unsigned u) {
    union { unsigned u; float f; } v; v.u = u & 0xffff0000u;
    return v.f;
}

// ---------------------------------------------------------------------------
// Count edges per (dst, rel) key.
// ---------------------------------------------------------------------------
__global__ __launch_bounds__(256) void count_kernel(const int* __restrict__ ei,
                                                    const int* __restrict__ et,
                                                    unsigned* __restrict__ cnt) {
    int e = blockIdx.x * 256 + threadIdx.x;
    if (e < N_EDGES) {
        int dst = ei[N_EDGES + e];
        int t   = et[e];
        atomicAdd(&cnt[(size_t)dst * NREL + t], 1u);
    }
}

// ---------------------------------------------------------------------------
// Exclusive prefix scan over cnt[NKEYS] -> offs[NKEYS], 3-kernel scheme.
// ---------------------------------------------------------------------------
__global__ __launch_bounds__(256) void scan1_kernel(const unsigned* __restrict__ cnt,
                                                    unsigned* __restrict__ offs,
                                                    unsigned* __restrict__ bsums) {
    __shared__ unsigned lds[256];
    int tid = threadIdx.x;
    int i0  = blockIdx.x * SCAN_CHUNK + tid * 4;
    unsigned v[4], incl[4];
    unsigned s = 0;
#pragma unroll
    for (int j = 0; j < 4; ++j) {
        v[j] = (i0 + j < NKEYS) ? cnt[i0 + j] : 0u;
        s += v[j];
        incl[j] = s;
    }
    lds[tid] = s;
    __syncthreads();
    for (int off = 1; off < 256; off <<= 1) {
        unsigned a = (tid >= off) ? lds[tid - off] : 0u;
        __syncthreads();
        lds[tid] += a;
        __syncthreads();
    }
    unsigned base = lds[tid] - s;
#pragma unroll
    for (int j = 0; j < 4; ++j) {
        if (i0 + j < NKEYS) offs[i0 + j] = base + incl[j] - v[j];
    }
    if (tid == 255) bsums[blockIdx.x] = lds[255];
}

__global__ __launch_bounds__(512) void scan2_kernel(unsigned* __restrict__ bsums) {
    __shared__ unsigned lds[512];
    int tid = threadIdx.x;
    unsigned v = (tid < SCAN_NBLK) ? bsums[tid] : 0u;
    lds[tid] = v;
    __syncthreads();
    for (int off = 1; off < 512; off <<= 1) {
        unsigned a = (tid >= off) ? lds[tid - off] : 0u;
        __syncthreads();
        lds[tid] += a;
        __syncthreads();
    }
    if (tid < SCAN_NBLK) bsums[tid] = lds[tid] - v;
}

__global__ __launch_bounds__(256) void scan3_kernel(unsigned* __restrict__ offs,
                                                    const unsigned* __restrict__ bsums) {
    int i0 = blockIdx.x * SCAN_CHUNK + threadIdx.x * 4;
    unsigned add = bsums[blockIdx.x];
#pragma unroll
    for (int j = 0; j < 4; ++j)
        if (i0 + j < NKEYS) offs[i0 + j] += add;
}

// ---------------------------------------------------------------------------
// Scatter src ids into bucket-sorted order (counting sort fill).
// ---------------------------------------------------------------------------
__global__ __launch_bounds__(256) void fill_kernel(const int* __restrict__ ei,
                                                   const int* __restrict__ et,
                                                   const unsigned* __restrict__ offs,
                                                   unsigned* __restrict__ fill,
                                                   int* __restrict__ sorted_src) {
    int e = blockIdx.x * 256 + threadIdx.x;
    if (e < N_EDGES) {
        int dst = ei[N_EDGES + e];
        int key = dst * NREL + et[e];
        unsigned p = offs[key] + atomicAdd(&fill[key], 1u);
        sorted_src[p] = ei[e];
    }
}

// ---------------------------------------------------------------------------
// Convert + transpose W into Bt[9][feat n][k] bf16 (Bt[8] = W_root^T).
// ---------------------------------------------------------------------------
__global__ __launch_bounds__(256) void bt_kernel(const float* __restrict__ W_rel,
                                                 const float* __restrict__ W_root,
                                                 ushort_t* __restrict__ Bt) {
    int i = blockIdx.x * 256 + threadIdx.x;
    if (i >= 9 * DIM * DIM) return;
    int r   = i >> 14;
    int rem = i & 16383;
    int n   = rem >> 7;
    int k   = rem & 127;
    const float* W = (r < NREL) ? (W_rel + (size_t)r * DIM * DIM) : W_root;
    Bt[i] = f2bf(W[(size_t)k * DIM + n]);
}

// ---------------------------------------------------------------------------
// x (fp32) -> xb (bf16), float4 -> uint2 per thread.
// ---------------------------------------------------------------------------
__global__ __launch_bounds__(256) void xb_kernel(const float* __restrict__ x,
                                                 ushort_t* __restrict__ xb) {
    int i = blockIdx.x * 256 + threadIdx.x;   // float4 index
    if (i >= N_NODES * DIM / 4) return;
    float4 v = ((const float4*)x)[i];
    unsigned lo = (unsigned)f2bf(v.x) | ((unsigned)f2bf(v.y) << 16);
    unsigned hi = (unsigned)f2bf(v.z) | ((unsigned)f2bf(v.w) << 16);
    ((uint2*)xb)[i] = make_uint2(lo, hi);
}

// ---------------------------------------------------------------------------
// Half-wave (32 lanes) per (node, rel) bucket: mean of xb[src] rows -> h bf16.
// ---------------------------------------------------------------------------
__global__ __launch_bounds__(256) void aggregate_kernel(const unsigned* __restrict__ offs,
                                                        const unsigned* __restrict__ cnt,
                                                        const int* __restrict__ sorted_src,
                                                        const ushort_t* __restrict__ xb,
                                                        ushort_t* __restrict__ h,
                                                        int r0, int cr) {
    int g  = blockIdx.x * 8 + (threadIdx.x >> 5);   // bucket id
    int sl = threadIdx.x & 31;                      // lane covers 4 feats
    int total = N_NODES * cr;
    if (g >= total) return;
    int n  = g / cr;
    int rl = g - n * cr;
    int key = n * NREL + r0 + rl;
    unsigned st = offs[key];
    unsigned mc = cnt[key];
    unsigned en = st + mc;
    float a0 = 0.f, a1 = 0.f, a2 = 0.f, a3 = 0.f;
    unsigned e = st;
    for (; e + 1 < en; e += 2) {
        int s0 = sorted_src[e];
        int s1 = sorted_src[e + 1];
        uint2 d0 = *(const uint2*)(xb + (size_t)s0 * DIM + sl * 4);
        uint2 d1 = *(const uint2*)(xb + (size_t)s1 * DIM + sl * 4);
        a0 += bf_lo(d0.x) + bf_lo(d1.x);
        a1 += bf_hi(d0.x) + bf_hi(d1.x);
        a2 += bf_lo(d0.y) + bf_lo(d1.y);
        a3 += bf_hi(d0.y) + bf_hi(d1.y);
    }
    if (e < en) {
        int s0 = sorted_src[e];
        uint2 d0 = *(const uint2*)(xb + (size_t)s0 * DIM + sl * 4);
        a0 += bf_lo(d0.x);
        a1 += bf_hi(d0.x);
        a2 += bf_lo(d0.y);
        a3 += bf_hi(d0.y);
    }
    float inv = 1.0f / fmaxf((float)mc, 1.0f);
    unsigned lo = (unsigned)f2bf(a0 * inv) | ((unsigned)f2bf(a1 * inv) << 16);
    unsigned hi = (unsigned)f2bf(a2 * inv) | ((unsigned)f2bf(a3 * inv) << 16);
    ((uint2*)(h + (size_t)g * DIM))[sl] = make_uint2(lo, hi);
}

// ---------------------------------------------------------------------------
// LDS-staged MFMA GEMM + optional fused bias+LN+ReLU.
// Block: 64 nodes x 128 feats, 4 waves (each wave: 16 nodes, all 128 feats).
// Per relation: batched stage of A (64x128 bf16) and B (128x128 bf16) into
// padded LDS (stride 272 B -> uniform bank spread), then 4 K-steps x 8 MFMA
// per wave between one barrier pair.  LDS 51 KB -> 3 blocks/CU.
// ---------------------------------------------------------------------------
__global__ __launch_bounds__(256) void gemm_ln_kernel(const ushort_t* __restrict__ h,
                                                      int cr, int r0,
                                                      const ushort_t* __restrict__ xb,
                                                      const ushort_t* __restrict__ Bt,
                                                      int include_root,
                                                      const float* __restrict__ bias,
                                                      const float* __restrict__ gamma,
                                                      const float* __restrict__ beta,
                                                      float* __restrict__ out,
                                                      int accumulate, int do_ln) {
    __shared__ __align__(16) ushort_t As[64 * A_STRIDE];    // 17.4 KB
    __shared__ __align__(16) ushort_t Bs[128 * B_STRIDE];   // 34.8 KB

    int tid  = threadIdx.x;
    int w    = tid >> 6;
    int lane = tid & 63;
    int m    = lane & 15;
    int quad = lane >> 4;
    int n0   = blockIdx.x * 64;

    f32x4 acc[8];
#pragma unroll
    for (int j = 0; j < 8; ++j) acc[j] = (f32x4){0.f, 0.f, 0.f, 0.f};

    int nrel = cr + include_root;
    for (int rr = 0; rr < nrel; ++rr) {
        int rel = (rr < cr) ? (r0 + rr) : NREL;

        // ---- stage B: 2048 x 16B chunks, 8 per thread (batched) ----
#pragma unroll
        for (int p = 0; p < 8; ++p) {
            int c = tid + 256 * p;
            int row = c >> 4, ch = c & 15;
            uint4 v = *(const uint4*)(Bt + ((size_t)rel * DIM + row) * DIM + ch * 8);
            *(uint4*)&Bs[row * B_STRIDE + ch * 8] = v;
        }
        // ---- stage A: 1024 x 16B chunks, 4 per thread (batched) ----
#pragma unroll
        for (int p = 0; p < 4; ++p) {
            int c = tid + 256 * p;
            int row = c >> 4, ch = c & 15;
            uint4 v = make_uint4(0, 0, 0, 0);
            int node = n0 + row;
            if (node < N_NODES) {
                const ushort_t* src = (rr < cr)
                    ? (h + ((size_t)node * cr + rr) * DIM)
                    : (xb + (size_t)node * DIM);
                v = *(const uint4*)(src + ch * 8);
            }
            *(uint4*)&As[row * A_STRIDE + ch * 8] = v;
        }
        __syncthreads();

        // ---- 32 MFMA per wave ----
#pragma unroll
        for (int t = 0; t < 4; ++t) {
            short8 af = *(const short8*)&As[(w * 16 + m) * A_STRIDE + t * 32 + quad * 8];
#pragma unroll
            for (int j = 0; j < 8; ++j) {
                short8 bf = *(const short8*)&Bs[(j * 16 + m) * B_STRIDE + t * 32 + quad * 8];
                acc[j] = __builtin_amdgcn_mfma_f32_16x16x32_bf16(af, bf, acc[j], 0, 0, 0);
            }
        }
        __syncthreads();
    }

    // ---- epilogue ----
    if (do_ln) {
        float bj[8], gj[8], btj[8];
#pragma unroll
        for (int j = 0; j < 8; ++j) {
            bj[j]  = bias[j * 16 + m];
            gj[j]  = gamma[j * 16 + m];
            btj[j] = beta[j * 16 + m];
        }
#pragma unroll
        for (int i = 0; i < 4; ++i) {
            float s = 0.f, sq = 0.f;
#pragma unroll
            for (int j = 0; j < 8; ++j) {
                float v = acc[j][i] + bj[j];
                s  += v;
                sq += v * v;
            }
#pragma unroll
            for (int off = 1; off < 16; off <<= 1) {
                s  += __shfl_xor(s, off, 64);
                sq += __shfl_xor(sq, off, 64);
            }
            float mean = s * (1.0f / DIM);
            float var  = sq * (1.0f / DIM) - mean * mean;
            float rstd = rsqrtf(var + LN_EPS);
            int node = n0 + w * 16 + quad * 4 + i;
            if (node < N_NODES) {
#pragma unroll
                for (int j = 0; j < 8; ++j) {
                    float v = acc[j][i] + bj[j];
                    v = (v - mean) * rstd * gj[j] + btj[j];
                    out[(size_t)node * DIM + j * 16 + m] = fmaxf(v, 0.f);
                }
            }
        }
    } else {
#pragma unroll
        for (int i = 0; i < 4; ++i) {
            int node = n0 + w * 16 + quad * 4 + i;
            if (node < N_NODES) {
#pragma unroll
                for (int j = 0; j < 8; ++j) {
                    size_t o = (size_t)node * DIM + j * 16 + m;
                    float v = acc[j][i];
                    if (accumulate) v += out[o];
                    out[o] = v;
                }
            }
        }
    }
}

// ---------------------------------------------------------------------------
// Standalone bias + LayerNorm + ReLU (fallback for chunked path).
// ---------------------------------------------------------------------------
__global__ __launch_bounds__(256) void ln_kernel(float* __restrict__ out,
                                                 const float* __restrict__ bias,
                                                 const float* __restrict__ gamma,
                                                 const float* __restrict__ beta) {
    int row  = blockIdx.x * 4 + (threadIdx.x >> 6);
    int lane = threadIdx.x & 63;
    if (row >= N_NODES) return;
    float2 v = *(float2*)(out + (size_t)row * DIM + lane * 2);
    float2 bi = *(const float2*)(bias + lane * 2);
    v.x += bi.x;
    v.y += bi.y;
    float s  = v.x + v.y;
    float sq = v.x * v.x + v.y * v.y;
#pragma unroll
    for (int off = 32; off > 0; off >>= 1) {
        s  += __shfl_xor(s, off, 64);
        sq += __shfl_xor(sq, off, 64);
    }
    float mean = s * (1.0f / DIM);
    float var  = sq * (1.0f / DIM) - mean * mean;
    float rstd = rsqrtf(var + LN_EPS);
    float2 g = *(const float2*)(gamma + lane * 2);
    float2 b = *(const float2*)(beta + lane * 2);
    v.x = fmaxf((v.x - mean) * rstd * g.x + b.x, 0.f);
    v.y = fmaxf((v.y - mean) * rstd * g.y + b.y, 0.f);
    *(float2*)(out + (size_t)row * DIM + lane * 2) = v;
}

// ---------------------------------------------------------------------------
extern "C" void kernel_launch(void* const* d_in, const int* in_sizes, int n_in,
                              void* d_out, int out_size, void* d_ws, size_t ws_size,
                              hipStream_t stream) {
    const float* x      = (const float*)d_in[0];
    const int*   ei     = (const int*)d_in[1];
    const int*   et     = (const int*)d_in[2];
    const float* W_rel  = (const float*)d_in[4];
    const float* W_root = (const float*)d_in[5];
    const float* bias   = (const float*)d_in[6];
    const float* gamma  = (const float*)d_in[7];
    const float* beta   = (const float*)d_in[8];
    float*       out    = (float*)d_out;

    // ---- workspace layout ----
    char* ws = (char*)d_ws;
    size_t off = 0;
    auto alloc = [&](size_t bytes) { char* p = ws + off; off = (off + bytes + 255) & ~(size_t)255; return p; };
    unsigned* cnt        = (unsigned*)alloc((size_t)NKEYS * 4);
    unsigned* offs       = (unsigned*)alloc((size_t)NKEYS * 4);
    unsigned* fill       = (unsigned*)alloc((size_t)NKEYS * 4);
    unsigned* bsums      = (unsigned*)alloc((size_t)SCAN_NBLK * 4);
    int*      sorted_src = (int*)alloc((size_t)N_EDGES * 4);
    ushort_t* Bt         = (ushort_t*)alloc((size_t)9 * DIM * DIM * 2);
    ushort_t* xb         = (ushort_t*)alloc((size_t)N_NODES * DIM * 2);
    size_t fixedOff = off;
    ushort_t* h = (ushort_t*)(ws + fixedOff);
    size_t availB = ws_size > fixedOff ? ws_size - fixedOff : 0;
    size_t perRel = (size_t)N_NODES * DIM * 2;   // 12.8 MB per relation (bf16)
    int chunkR = (int)(availB / perRel);
    if (chunkR > NREL) chunkR = NREL;
    if (chunkR < 1)    chunkR = 1;

    // ---- build counting sort ----
    hipMemsetAsync(cnt, 0, (size_t)NKEYS * 4, stream);
    hipMemsetAsync(fill, 0, (size_t)NKEYS * 4, stream);
    count_kernel<<<(N_EDGES + 255) / 256, 256, 0, stream>>>(ei, et, cnt);
    scan1_kernel<<<SCAN_NBLK, 256, 0, stream>>>(cnt, offs, bsums);
    scan2_kernel<<<1, 512, 0, stream>>>(bsums);
    scan3_kernel<<<SCAN_NBLK, 256, 0, stream>>>(offs, bsums);
    fill_kernel<<<(N_EDGES + 255) / 256, 256, 0, stream>>>(ei, et, offs, fill, sorted_src);

    // ---- precompute bf16 operands ----
    bt_kernel<<<(9 * DIM * DIM + 255) / 256, 256, 0, stream>>>(W_rel, W_root, Bt);
    xb_kernel<<<(N_NODES * DIM / 4 + 255) / 256, 256, 0, stream>>>(x, xb);

    int gemmGrid = (N_NODES + 63) / 64;

    if (chunkR >= NREL) {
        int nbuck = N_NODES * NREL;
        aggregate_kernel<<<(nbuck + 7) / 8, 256, 0, stream>>>(offs, cnt, sorted_src, xb, h, 0, NREL);
        gemm_ln_kernel<<<gemmGrid, 256, 0, stream>>>(h, NREL, 0, xb, Bt, 1,
                                                     bias, gamma, beta, out, 0, 1);
    } else {
        for (int r0 = 0; r0 < NREL; r0 += chunkR) {
            int cr = (NREL - r0 < chunkR) ? (NREL - r0) : chunkR;
            int nbuck = N_NODES * cr;
            aggregate_kernel<<<(nbuck + 7) / 8, 256, 0, stream>>>(offs, cnt, sorted_src, xb, h, r0, cr);
            int include_root = (r0 + cr == NREL) ? 1 : 0;
            gemm_ln_kernel<<<gemmGrid, 256, 0, stream>>>(h, cr, r0, xb, Bt, include_root,
                                                         bias, gamma, beta, out,
                                                         r0 > 0 ? 1 : 0, 0);
        }
        ln_kernel<<<(N_NODES + 3) / 4, 256, 0, stream>>>(out, bias, gamma, beta);
    }
}

// Round 7
// 350.955 us; speedup vs baseline: 1.6552x; 1.1600x over previous
//
#include <hip/hip_runtime.h>
#include <hip/hip_bf16.h>
#include <cstdint>

#define N_NODES 50000
#define N_EDGES 1600000
#define DIM 128
#define NREL 8
#define LN_EPS 1e-5f

#define NKEYS (N_NODES * NREL)          // 400000
#define SCAN_CHUNK 1024                 // elems per scan block (256 thr x 4)
#define SCAN_NBLK ((NKEYS + SCAN_CHUNK - 1) / SCAN_CHUNK)  // 391

#define A_STRIDE 136                    // ushorts per LDS A row (128 + 8 pad)
#define B_STRIDE 136                    // ushorts per LDS B row

#define XB_BLOCKS 6250                  // N_NODES*DIM/4 / 256
#define BT_BLOCKS 576                   // 9*128*128 / 256

typedef unsigned short ushort_t;
typedef short short8 __attribute__((ext_vector_type(8)));
typedef float f32x4 __attribute__((ext_vector_type(4)));

__device__ inline ushort_t f2bf(float f) {
    union { float f; unsigned u; } v; v.f = f;
    unsigned r = (v.u + 0x7FFFu + ((v.u >> 16) & 1u)) >> 16;
    return (ushort_t)r;
}
__device__ inline float bf_lo(unsigned u) {
    union { unsigned u; float f; } v; v.u = u << 16;
    return v.f;
}
__device__ inline float bf_hi(unsigned u) {
    union { unsigned u; float f; } v; v.u = u & 0xffff0000u;
    return v.f;
}

// ---------------------------------------------------------------------------
// Fused prep: xb (x fp32 -> bf16) and Bt (W transposed bf16), one launch.
// ---------------------------------------------------------------------------
__global__ __launch_bounds__(256) void prep_kernel(const float* __restrict__ x,
                                                   ushort_t* __restrict__ xb,
                                                   const float* __restrict__ W_rel,
                                                   const float* __restrict__ W_root,
                                                   ushort_t* __restrict__ Bt) {
    int b = blockIdx.x;
    if (b < XB_BLOCKS) {
        int i = b * 256 + threadIdx.x;            // float4 index
        float4 v = ((const float4*)x)[i];
        unsigned lo = (unsigned)f2bf(v.x) | ((unsigned)f2bf(v.y) << 16);
        unsigned hi = (unsigned)f2bf(v.z) | ((unsigned)f2bf(v.w) << 16);
        ((uint2*)xb)[i] = make_uint2(lo, hi);
    } else {
        int i = (b - XB_BLOCKS) * 256 + threadIdx.x;
        int r   = i >> 14;
        int rem = i & 16383;
        int n   = rem >> 7;
        int k   = rem & 127;
        const float* W = (r < NREL) ? (W_rel + (size_t)r * DIM * DIM) : W_root;
        Bt[i] = f2bf(W[(size_t)k * DIM + n]);
    }
}

// ---------------------------------------------------------------------------
// Count edges per key AND record each edge's within-bucket rank, packed as
// (key << 12) | rank. rank < 4096 (uniform graph: Poisson(4) per bucket).
// ---------------------------------------------------------------------------
__global__ __launch_bounds__(256) void count_rank_kernel(const int* __restrict__ ei,
                                                         const int* __restrict__ et,
                                                         unsigned* __restrict__ cnt,
                                                         unsigned* __restrict__ krk) {
    int e = blockIdx.x * 256 + threadIdx.x;
    if (e < N_EDGES) {
        int dst = ei[N_EDGES + e];
        unsigned key = (unsigned)dst * NREL + (unsigned)et[e];
        unsigned rank = atomicAdd(&cnt[key], 1u);
        krk[e] = (key << 12) | rank;
    }
}

// ---------------------------------------------------------------------------
// Block-local exclusive scan: meta[key] = (local_excl_offset, cnt), plus
// per-block sums. Consumers add bsums[key>>10] for the global offset.
// ---------------------------------------------------------------------------
__global__ __launch_bounds__(256) void scan1_kernel(const unsigned* __restrict__ cnt,
                                                    uint2* __restrict__ meta,
                                                    unsigned* __restrict__ bsums) {
    __shared__ unsigned lds[256];
    int tid = threadIdx.x;
    int i0  = blockIdx.x * SCAN_CHUNK + tid * 4;
    unsigned v[4], incl[4];
    unsigned s = 0;
#pragma unroll
    for (int j = 0; j < 4; ++j) {
        v[j] = (i0 + j < NKEYS) ? cnt[i0 + j] : 0u;
        s += v[j];
        incl[j] = s;
    }
    lds[tid] = s;
    __syncthreads();
    for (int off = 1; off < 256; off <<= 1) {
        unsigned a = (tid >= off) ? lds[tid - off] : 0u;
        __syncthreads();
        lds[tid] += a;
        __syncthreads();
    }
    unsigned base = lds[tid] - s;
#pragma unroll
    for (int j = 0; j < 4; ++j) {
        if (i0 + j < NKEYS) meta[i0 + j] = make_uint2(base + incl[j] - v[j], v[j]);
    }
    if (tid == 255) bsums[blockIdx.x] = lds[255];
}

__global__ __launch_bounds__(512) void scan2_kernel(unsigned* __restrict__ bsums) {
    __shared__ unsigned lds[512];
    int tid = threadIdx.x;
    unsigned v = (tid < SCAN_NBLK) ? bsums[tid] : 0u;
    lds[tid] = v;
    __syncthreads();
    for (int off = 1; off < 512; off <<= 1) {
        unsigned a = (tid >= off) ? lds[tid - off] : 0u;
        __syncthreads();
        lds[tid] += a;
        __syncthreads();
    }
    if (tid < SCAN_NBLK) bsums[tid] = lds[tid] - v;
}

// ---------------------------------------------------------------------------
// Atomic-free counting-sort fill: p = meta[key].x + bsums[key>>10] + rank.
// ---------------------------------------------------------------------------
__global__ __launch_bounds__(256) void fill_kernel(const int* __restrict__ ei,
                                                   const unsigned* __restrict__ krk,
                                                   const uint2* __restrict__ meta,
                                                   const unsigned* __restrict__ bsums,
                                                   int* __restrict__ sorted_src) {
    int e = blockIdx.x * 256 + threadIdx.x;
    if (e < N_EDGES) {
        unsigned kr   = krk[e];
        unsigned key  = kr >> 12;
        unsigned rank = kr & 4095u;
        unsigned p = meta[key].x + bsums[key >> 10] + rank;
        sorted_src[p] = ei[e];
    }
}

// ---------------------------------------------------------------------------
// Half-wave (32 lanes) per (node, rel) bucket: mean of xb[src] rows -> h bf16.
// ---------------------------------------------------------------------------
__global__ __launch_bounds__(256) void aggregate_kernel(const uint2* __restrict__ meta,
                                                        const unsigned* __restrict__ bsums,
                                                        const int* __restrict__ sorted_src,
                                                        const ushort_t* __restrict__ xb,
                                                        ushort_t* __restrict__ h,
                                                        int r0, int cr) {
    int g  = blockIdx.x * 8 + (threadIdx.x >> 5);   // bucket id
    int sl = threadIdx.x & 31;                      // lane covers 4 feats
    int total = N_NODES * cr;
    if (g >= total) return;
    int n  = g / cr;
    int rl = g - n * cr;
    unsigned key = (unsigned)n * NREL + r0 + rl;
    uint2 md = meta[key];
    unsigned st = md.x + bsums[key >> 10];
    unsigned mc = md.y;
    unsigned en = st + mc;
    float a0 = 0.f, a1 = 0.f, a2 = 0.f, a3 = 0.f;
    unsigned e = st;
    for (; e + 1 < en; e += 2) {
        int s0 = sorted_src[e];
        int s1 = sorted_src[e + 1];
        uint2 d0 = *(const uint2*)(xb + (size_t)s0 * DIM + sl * 4);
        uint2 d1 = *(const uint2*)(xb + (size_t)s1 * DIM + sl * 4);
        a0 += bf_lo(d0.x) + bf_lo(d1.x);
        a1 += bf_hi(d0.x) + bf_hi(d1.x);
        a2 += bf_lo(d0.y) + bf_lo(d1.y);
        a3 += bf_hi(d0.y) + bf_hi(d1.y);
    }
    if (e < en) {
        int s0 = sorted_src[e];
        uint2 d0 = *(const uint2*)(xb + (size_t)s0 * DIM + sl * 4);
        a0 += bf_lo(d0.x);
        a1 += bf_hi(d0.x);
        a2 += bf_lo(d0.y);
        a3 += bf_hi(d0.y);
    }
    float inv = 1.0f / fmaxf((float)mc, 1.0f);
    unsigned lo = (unsigned)f2bf(a0 * inv) | ((unsigned)f2bf(a1 * inv) << 16);
    unsigned hi = (unsigned)f2bf(a2 * inv) | ((unsigned)f2bf(a3 * inv) << 16);
    ((uint2*)(h + (size_t)g * DIM))[sl] = make_uint2(lo, hi);
}

// ---------------------------------------------------------------------------
// LDS-staged MFMA GEMM + optional fused bias+LN+ReLU (unchanged from R5 —
// matched prediction). 64 nodes x 128 feats, 4 waves, 51 KB LDS, 3 blocks/CU.
// ---------------------------------------------------------------------------
__global__ __launch_bounds__(256) void gemm_ln_kernel(const ushort_t* __restrict__ h,
                                                      int cr, int r0,
                                                      const ushort_t* __restrict__ xb,
                                                      const ushort_t* __restrict__ Bt,
                                                      int include_root,
                                                      const float* __restrict__ bias,
                                                      const float* __restrict__ gamma,
                                                      const float* __restrict__ beta,
                                                      float* __restrict__ out,
                                                      int accumulate, int do_ln) {
    __shared__ __align__(16) ushort_t As[64 * A_STRIDE];    // 17.4 KB
    __shared__ __align__(16) ushort_t Bs[128 * B_STRIDE];   // 34.8 KB

    int tid  = threadIdx.x;
    int w    = tid >> 6;
    int lane = tid & 63;
    int m    = lane & 15;
    int quad = lane >> 4;
    int n0   = blockIdx.x * 64;

    f32x4 acc[8];
#pragma unroll
    for (int j = 0; j < 8; ++j) acc[j] = (f32x4){0.f, 0.f, 0.f, 0.f};

    int nrel = cr + include_root;
    for (int rr = 0; rr < nrel; ++rr) {
        int rel = (rr < cr) ? (r0 + rr) : NREL;

        // ---- stage B: 2048 x 16B chunks, 8 per thread (batched) ----
#pragma unroll
        for (int p = 0; p < 8; ++p) {
            int c = tid + 256 * p;
            int row = c >> 4, ch = c & 15;
            uint4 v = *(const uint4*)(Bt + ((size_t)rel * DIM + row) * DIM + ch * 8);
            *(uint4*)&Bs[row * B_STRIDE + ch * 8] = v;
        }
        // ---- stage A: 1024 x 16B chunks, 4 per thread (batched) ----
#pragma unroll
        for (int p = 0; p < 4; ++p) {
            int c = tid + 256 * p;
            int row = c >> 4, ch = c & 15;
            uint4 v = make_uint4(0, 0, 0, 0);
            int node = n0 + row;
            if (node < N_NODES) {
                const ushort_t* src = (rr < cr)
                    ? (h + ((size_t)node * cr + rr) * DIM)
                    : (xb + (size_t)node * DIM);
                v = *(const uint4*)(src + ch * 8);
            }
            *(uint4*)&As[row * A_STRIDE + ch * 8] = v;
        }
        __syncthreads();

        // ---- 32 MFMA per wave ----
#pragma unroll
        for (int t = 0; t < 4; ++t) {
            short8 af = *(const short8*)&As[(w * 16 + m) * A_STRIDE + t * 32 + quad * 8];
#pragma unroll
            for (int j = 0; j < 8; ++j) {
                short8 bf = *(const short8*)&Bs[(j * 16 + m) * B_STRIDE + t * 32 + quad * 8];
                acc[j] = __builtin_amdgcn_mfma_f32_16x16x32_bf16(af, bf, acc[j], 0, 0, 0);
            }
        }
        __syncthreads();
    }

    // ---- epilogue ----
    if (do_ln) {
        float bj[8], gj[8], btj[8];
#pragma unroll
        for (int j = 0; j < 8; ++j) {
            bj[j]  = bias[j * 16 + m];
            gj[j]  = gamma[j * 16 + m];
            btj[j] = beta[j * 16 + m];
        }
#pragma unroll
        for (int i = 0; i < 4; ++i) {
            float s = 0.f, sq = 0.f;
#pragma unroll
            for (int j = 0; j < 8; ++j) {
                float v = acc[j][i] + bj[j];
                s  += v;
                sq += v * v;
            }
#pragma unroll
            for (int off = 1; off < 16; off <<= 1) {
                s  += __shfl_xor(s, off, 64);
                sq += __shfl_xor(sq, off, 64);
            }
            float mean = s * (1.0f / DIM);
            float var  = sq * (1.0f / DIM) - mean * mean;
            float rstd = rsqrtf(var + LN_EPS);
            int node = n0 + w * 16 + quad * 4 + i;
            if (node < N_NODES) {
#pragma unroll
                for (int j = 0; j < 8; ++j) {
                    float v = acc[j][i] + bj[j];
                    v = (v - mean) * rstd * gj[j] + btj[j];
                    out[(size_t)node * DIM + j * 16 + m] = fmaxf(v, 0.f);
                }
            }
        }
    } else {
#pragma unroll
        for (int i = 0; i < 4; ++i) {
            int node = n0 + w * 16 + quad * 4 + i;
            if (node < N_NODES) {
#pragma unroll
                for (int j = 0; j < 8; ++j) {
                    size_t o = (size_t)node * DIM + j * 16 + m;
                    float v = acc[j][i];
                    if (accumulate) v += out[o];
                    out[o] = v;
                }
            }
        }
    }
}

// ---------------------------------------------------------------------------
// Standalone bias + LayerNorm + ReLU (fallback for chunked path).
// ---------------------------------------------------------------------------
__global__ __launch_bounds__(256) void ln_kernel(float* __restrict__ out,
                                                 const float* __restrict__ bias,
                                                 const float* __restrict__ gamma,
                                                 const float* __restrict__ beta) {
    int row  = blockIdx.x * 4 + (threadIdx.x >> 6);
    int lane = threadIdx.x & 63;
    if (row >= N_NODES) return;
    float2 v = *(float2*)(out + (size_t)row * DIM + lane * 2);
    float2 bi = *(const float2*)(bias + lane * 2);
    v.x += bi.x;
    v.y += bi.y;
    float s  = v.x + v.y;
    float sq = v.x * v.x + v.y * v.y;
#pragma unroll
    for (int off = 32; off > 0; off >>= 1) {
        s  += __shfl_xor(s, off, 64);
        sq += __shfl_xor(sq, off, 64);
    }
    float mean = s * (1.0f / DIM);
    float var  = sq * (1.0f / DIM) - mean * mean;
    float rstd = rsqrtf(var + LN_EPS);
    float2 g = *(const float2*)(gamma + lane * 2);
    float2 b = *(const float2*)(beta + lane * 2);
    v.x = fmaxf((v.x - mean) * rstd * g.x + b.x, 0.f);
    v.y = fmaxf((v.y - mean) * rstd * g.y + b.y, 0.f);
    *(float2*)(out + (size_t)row * DIM + lane * 2) = v;
}

// ---------------------------------------------------------------------------
extern "C" void kernel_launch(void* const* d_in, const int* in_sizes, int n_in,
                              void* d_out, int out_size, void* d_ws, size_t ws_size,
                              hipStream_t stream) {
    const float* x      = (const float*)d_in[0];
    const int*   ei     = (const int*)d_in[1];
    const int*   et     = (const int*)d_in[2];
    const float* W_rel  = (const float*)d_in[4];
    const float* W_root = (const float*)d_in[5];
    const float* bias   = (const float*)d_in[6];
    const float* gamma  = (const float*)d_in[7];
    const float* beta   = (const float*)d_in[8];
    float*       out    = (float*)d_out;

    // ---- workspace layout ----
    char* ws = (char*)d_ws;
    size_t off = 0;
    auto alloc = [&](size_t bytes) { char* p = ws + off; off = (off + bytes + 255) & ~(size_t)255; return p; };
    unsigned* cnt        = (unsigned*)alloc((size_t)NKEYS * 4);
    uint2*    meta       = (uint2*)alloc((size_t)NKEYS * 8);
    unsigned* bsums      = (unsigned*)alloc((size_t)SCAN_NBLK * 4);
    unsigned* krk        = (unsigned*)alloc((size_t)N_EDGES * 4);
    int*      sorted_src = (int*)alloc((size_t)N_EDGES * 4);
    ushort_t* Bt         = (ushort_t*)alloc((size_t)9 * DIM * DIM * 2);
    ushort_t* xb         = (ushort_t*)alloc((size_t)N_NODES * DIM * 2);
    size_t fixedOff = off;
    ushort_t* h = (ushort_t*)(ws + fixedOff);
    size_t availB = ws_size > fixedOff ? ws_size - fixedOff : 0;
    size_t perRel = (size_t)N_NODES * DIM * 2;   // 12.8 MB per relation (bf16)
    int chunkR = (int)(availB / perRel);
    if (chunkR > NREL) chunkR = NREL;
    if (chunkR < 1)    chunkR = 1;

    // ---- build counting sort (rank recorded during count; no fill atomic) ----
    hipMemsetAsync(cnt, 0, (size_t)NKEYS * 4, stream);
    prep_kernel<<<XB_BLOCKS + BT_BLOCKS, 256, 0, stream>>>(x, xb, W_rel, W_root, Bt);
    count_rank_kernel<<<(N_EDGES + 255) / 256, 256, 0, stream>>>(ei, et, cnt, krk);
    scan1_kernel<<<SCAN_NBLK, 256, 0, stream>>>(cnt, meta, bsums);
    scan2_kernel<<<1, 512, 0, stream>>>(bsums);
    fill_kernel<<<(N_EDGES + 255) / 256, 256, 0, stream>>>(ei, krk, meta, bsums, sorted_src);

    int gemmGrid = (N_NODES + 63) / 64;

    if (chunkR >= NREL) {
        int nbuck = N_NODES * NREL;
        aggregate_kernel<<<(nbuck + 7) / 8, 256, 0, stream>>>(meta, bsums, sorted_src, xb, h, 0, NREL);
        gemm_ln_kernel<<<gemmGrid, 256, 0, stream>>>(h, NREL, 0, xb, Bt, 1,
                                                     bias, gamma, beta, out, 0, 1);
    } else {
        for (int r0 = 0; r0 < NREL; r0 += chunkR) {
            int cr = (NREL - r0 < chunkR) ? (NREL - r0) : chunkR;
            int nbuck = N_NODES * cr;
            aggregate_kernel<<<(nbuck + 7) / 8, 256, 0, stream>>>(meta, bsums, sorted_src, xb, h, r0, cr);
            int include_root = (r0 + cr == NREL) ? 1 : 0;
            gemm_ln_kernel<<<gemmGrid, 256, 0, stream>>>(h, cr, r0, xb, Bt, include_root,
                                                         bias, gamma, beta, out,
                                                         r0 > 0 ? 1 : 0, 0);
        }
        ln_kernel<<<(N_NODES + 3) / 4, 256, 0, stream>>>(out, bias, gamma, beta);
    }
}